// Round 1
// baseline (383.946 us; speedup 1.0000x reference)
//
#include <hip/hip_runtime.h>
#include <cstdint>

typedef uint16_t u16;
typedef __attribute__((ext_vector_type(8))) short bf16x8;
typedef __attribute__((ext_vector_type(4))) short bf16x4;
typedef __attribute__((ext_vector_type(4))) float f32x4;

#define LOG2E 1.44269504088896340736f

__device__ __forceinline__ u16 f2bf(float x) {
  union { float f; uint32_t u; } v; v.f = x;
  uint32_t r = (v.u + 0x7fffu + ((v.u >> 16) & 1u)) >> 16;
  return (u16)r;
}

// async global->LDS, 16B per lane. LDS dest is wave-uniform base + lane*16.
__device__ __forceinline__ void async16(void* lds, const void* g) {
  __builtin_amdgcn_global_load_lds((const __attribute__((address_space(1))) void*)g,
                                   (__attribute__((address_space(3))) void*)lds, 16, 0, 0);
}

// ---------------- elementwise f32 -> bf16 ----------------
__global__ __launch_bounds__(256) void k_f32_to_bf16(const float* __restrict__ in,
                                                     u16* __restrict__ out, int n4) {
  int i = blockIdx.x * 256 + threadIdx.x;
  if (i < n4) {
    float4 v = ((const float4*)in)[i];
    bf16x4 o;
    o[0] = (short)f2bf(v.x); o[1] = (short)f2bf(v.y);
    o[2] = (short)f2bf(v.z); o[3] = (short)f2bf(v.w);
    *(bf16x4*)(out + (size_t)i * 4) = o;
  }
}

// ---------------- tiled transpose -> bf16 ----------------
// in: slab matrices R x C (C = gridDim.y*64), row stride = rstride
// out[z][c][r] contiguous (slab size C*R). in_base = (z/sph)*slab_hi + (z%sph)*slab_lo
__global__ __launch_bounds__(256) void k_transpose_bf16(const void* __restrict__ in,
                                                        int in_is_f32, u16* __restrict__ out,
                                                        int rstride, int R, int sph,
                                                        long slab_lo, long slab_hi) {
  __shared__ u16 tile[64 * 72];
  const int t = threadIdx.x;
  const long z = blockIdx.z;
  const long in_base = (z / sph) * slab_hi + (z % sph) * slab_lo;
  const long out_base = z * (long)R * (long)(gridDim.y * 64);
  const int r0 = blockIdx.x * 64, c0 = blockIdx.y * 64;
  for (int e = t; e < 4096; e += 256) {
    int rr = e >> 6, cc = e & 63;
    long src = in_base + (long)(r0 + rr) * rstride + c0 + cc;
    u16 w = in_is_f32 ? f2bf(((const float*)in)[src]) : ((const u16*)in)[src];
    tile[rr * 72 + cc] = w;
  }
  __syncthreads();
  for (int s = t; s < 512; s += 256) {
    int cc = s >> 3, r8 = (s & 7) << 3;
    bf16x8 p;
    #pragma unroll
    for (int j = 0; j < 8; ++j) p[j] = (short)tile[(r8 + j) * 72 + cc];
    *(bf16x8*)(out + out_base + (long)(c0 + cc) * R + r0 + r8) = p;
  }
}

// ---------------- GEMM: C(MxN) = A(MxK) * Bt(NxK)^T ----------------
// A, Bt bf16 row-major. If Cf != nullptr: f32 out + bias. Else bf16 out * scale.
__global__ __launch_bounds__(256) void k_gemm_bt(const u16* __restrict__ A,
                                                 const u16* __restrict__ Bt,
                                                 u16* __restrict__ Cbf, float* __restrict__ Cf,
                                                 const float* __restrict__ bias,
                                                 int M, int N, int K, float scale) {
  __shared__ __align__(16) u16 As[128 * 32];
  __shared__ __align__(16) u16 Bs[128 * 32];
  const int t = threadIdx.x, lane = t & 63, quad = lane >> 4, l16 = lane & 15;
  const int wave = t >> 6, wy = wave >> 1, wx = wave & 1;
  const int m0 = blockIdx.y * 128, n0 = blockIdx.x * 128;
  const int wbase = t & 192;
  f32x4 acc[4][4] = {};
  for (int k0 = 0; k0 < K; k0 += 32) {
    __syncthreads();
    #pragma unroll
    for (int i = 0; i < 2; ++i) {
      int sb = i * 256 + wbase;
      int s = sb + lane;
      int row = s >> 2, c = s & 3;
      async16(As + sb * 8, A + (long)(m0 + row) * K + k0 + c * 8);
      async16(Bs + sb * 8, Bt + (long)(n0 + row) * K + k0 + c * 8);
    }
    __syncthreads();
    bf16x8 af[4], bfr[4];
    #pragma unroll
    for (int mt = 0; mt < 4; ++mt)
      af[mt] = *(const bf16x8*)(As + (wy * 64 + mt * 16 + l16) * 32 + quad * 8);
    #pragma unroll
    for (int nt = 0; nt < 4; ++nt)
      bfr[nt] = *(const bf16x8*)(Bs + (wx * 64 + nt * 16 + l16) * 32 + quad * 8);
    #pragma unroll
    for (int mt = 0; mt < 4; ++mt)
      #pragma unroll
      for (int nt = 0; nt < 4; ++nt)
        acc[mt][nt] = __builtin_amdgcn_mfma_f32_16x16x32_bf16(af[mt], bfr[nt], acc[mt][nt], 0, 0, 0);
  }
  #pragma unroll
  for (int mt = 0; mt < 4; ++mt)
    #pragma unroll
    for (int nt = 0; nt < 4; ++nt) {
      int col = n0 + wx * 64 + nt * 16 + l16;
      #pragma unroll
      for (int r = 0; r < 4; ++r) {
        int row = m0 + wy * 64 + mt * 16 + quad * 4 + r;
        float v = acc[mt][nt][r];
        if (Cf) Cf[(long)row * N + col] = v + bias[col];
        else Cbf[(long)row * N + col] = f2bf(v * scale);
      }
    }
}

// ---------------- flash attention ----------------
// Qp, Kp: (B,L,H,64) bf16 (Qp pre-scaled by 1/8). Vt: (B*H, 64, L) bf16.
// ctx out: (B,L,H,64) bf16, softmax-normalized.
__global__ __launch_bounds__(256) void k_flash(const u16* __restrict__ Qp,
                                               const u16* __restrict__ Kp,
                                               const u16* __restrict__ Vt,
                                               u16* __restrict__ ctx) {
  __shared__ __align__(16) u16 qs[64 * 64];
  __shared__ __align__(16) u16 ks[64 * 64];
  __shared__ __align__(16) u16 vs[64 * 64];
  __shared__ __align__(16) u16 pt[4 * 64 * 20];  // per-wave P^T, row stride 20 shorts (40B)
  const int t = threadIdx.x, lane = t & 63, quad = lane >> 4, l16 = lane & 15;
  const int wave = t >> 6, wbase = t & 192;
  const int bh = blockIdx.x, b = bh >> 4, h = bh & 15;
  const int q0 = blockIdx.y * 64;

  // stage Q tile (64 x 64), XOR-swizzled chunks: LDS pos (row, p) holds chunk p^(row&7)
  {
    long gb = (long)(b * 2048 + q0) * 1024 + h * 64;
    #pragma unroll
    for (int i = 0; i < 2; ++i) {
      int sb = i * 256 + wbase, s = sb + lane;
      int row = s >> 3, pos = s & 7, c = pos ^ (row & 7);
      async16(qs + sb * 8, Qp + gb + (long)row * 1024 + c * 8);
    }
  }
  __syncthreads();
  bf16x8 qf[2];
  {
    int m = wave * 16 + l16;
    #pragma unroll
    for (int kh = 0; kh < 2; ++kh) {
      int pos = (kh * 4 + quad) ^ (m & 7);
      qf[kh] = *(const bf16x8*)(qs + m * 64 + pos * 8);
    }
  }

  float mrow[4] = {-3e38f, -3e38f, -3e38f, -3e38f};
  float lrow[4] = {0.f, 0.f, 0.f, 0.f};
  f32x4 o[4] = {};
  u16* ptw = pt + wave * 1280;

  for (int kt = 0; kt < 32; ++kt) {
    const int kv0 = kt * 64;
    __syncthreads();
    {
      long gk = (long)(b * 2048 + kv0) * 1024 + h * 64;
      long gv = (long)bh * 131072 + kv0;
      #pragma unroll
      for (int i = 0; i < 2; ++i) {
        int sb = i * 256 + wbase, s = sb + lane;
        int row = s >> 3, pos = s & 7, c = pos ^ (row & 7);
        async16(ks + sb * 8, Kp + gk + (long)row * 1024 + c * 8);
        async16(vs + sb * 8, Vt + gv + (long)row * 2048 + c * 8);
      }
    }
    __syncthreads();

    // S(16x64) = Q @ K^T  (scale pre-folded into Q)
    f32x4 s4[4];
    #pragma unroll
    for (int nt = 0; nt < 4; ++nt) {
      f32x4 accs = {};
      #pragma unroll
      for (int kh = 0; kh < 2; ++kh) {
        int rowk = nt * 16 + l16;
        int pos = (kh * 4 + quad) ^ (rowk & 7);
        bf16x8 kf = *(const bf16x8*)(ks + rowk * 64 + pos * 8);
        accs = __builtin_amdgcn_mfma_f32_16x16x32_bf16(qf[kh], kf, accs, 0, 0, 0);
      }
      s4[nt] = accs;
    }

    // online softmax; row r of this wave's 16-row tile is (quad*4+r)
    #pragma unroll
    for (int r = 0; r < 4; ++r) {
      float mx = fmaxf(fmaxf(s4[0][r], s4[1][r]), fmaxf(s4[2][r], s4[3][r]));
      #pragma unroll
      for (int d = 1; d < 16; d <<= 1) mx = fmaxf(mx, __shfl_xor(mx, d));
      float mnew = fmaxf(mrow[r], mx);
      float alpha = __builtin_amdgcn_exp2f((mrow[r] - mnew) * LOG2E);
      mrow[r] = mnew;
      float ps = 0.f;
      #pragma unroll
      for (int nt = 0; nt < 4; ++nt) {
        float p = __builtin_amdgcn_exp2f((s4[nt][r] - mnew) * LOG2E);
        s4[nt][r] = p;
        ps += p;
      }
      #pragma unroll
      for (int d = 1; d < 16; d <<= 1) ps += __shfl_xor(ps, d);
      lrow[r] = lrow[r] * alpha + ps;
      #pragma unroll
      for (int nt = 0; nt < 4; ++nt) o[nt][r] *= alpha;
    }

    // P^T round-trip through LDS (C-layout -> A-layout)
    #pragma unroll
    for (int nt = 0; nt < 4; ++nt) {
      int kv = nt * 16 + l16;
      bf16x4 pk;
      #pragma unroll
      for (int r = 0; r < 4; ++r) pk[r] = (short)f2bf(s4[nt][r]);
      *(bf16x4*)(ptw + kv * 20 + quad * 4) = pk;
    }

    // O(16x64) += P(16x64) @ V(64x64)
    #pragma unroll
    for (int kh = 0; kh < 2; ++kh) {
      bf16x8 pa;
      #pragma unroll
      for (int j = 0; j < 8; ++j)
        pa[j] = (short)ptw[(kh * 32 + quad * 8 + j) * 20 + l16];
      #pragma unroll
      for (int nt = 0; nt < 4; ++nt) {
        int rowv = nt * 16 + l16;
        int pos = (kh * 4 + quad) ^ (rowv & 7);
        bf16x8 vf = *(const bf16x8*)(vs + rowv * 64 + pos * 8);
        o[nt] = __builtin_amdgcn_mfma_f32_16x16x32_bf16(pa, vf, o[nt], 0, 0, 0);
      }
    }
  }

  // normalize + write ctx (B,L,H,64)
  #pragma unroll
  for (int nt = 0; nt < 4; ++nt)
    #pragma unroll
    for (int r = 0; r < 4; ++r) {
      int q = q0 + wave * 16 + quad * 4 + r;
      long idx = (long)(b * 2048 + q) * 1024 + h * 64 + nt * 16 + l16;
      ctx[idx] = f2bf(o[nt][r] / lrow[r]);
    }
}

extern "C" void kernel_launch(void* const* d_in, const int* in_sizes, int n_in,
                              void* d_out, int out_size, void* d_ws, size_t ws_size,
                              hipStream_t stream) {
  const float* query = (const float*)d_in[0];
  const float* key   = (const float*)d_in[1];
  const float* value = (const float*)d_in[2];
  const float* Wq    = (const float*)d_in[3];
  const float* Wk    = (const float*)d_in[4];
  const float* Wv    = (const float*)d_in[5];
  const float* out_w = (const float*)d_in[6];
  const float* out_b = (const float*)d_in[7];
  // d_in[8] = coupling: unused — per-head scalar bias is softmax-invariant.
  float* out = (float*)d_out;

  char* ws = (char*)d_ws;
  size_t off = 0;
  auto alloc = [&](size_t bytes) {
    void* p = ws + off;
    off += (bytes + 255) & ~(size_t)255;
    return p;
  };
  u16* qb  = (u16*)alloc(4096L * 1024 * 2);
  u16* kb  = (u16*)alloc(4096L * 1024 * 2);
  u16* vb  = (u16*)alloc(4096L * 1024 * 2);
  u16* wtq = (u16*)alloc(1024L * 1024 * 2);
  u16* wtk = (u16*)alloc(1024L * 1024 * 2);
  u16* wtv = (u16*)alloc(1024L * 1024 * 2);
  u16* wto = (u16*)alloc(1024L * 1024 * 2);
  u16* Qp  = (u16*)alloc(4096L * 1024 * 2);
  u16* Kp  = (u16*)alloc(4096L * 1024 * 2);
  u16* Vp  = (u16*)alloc(4096L * 1024 * 2);
  u16* Vtb = (u16*)alloc(4096L * 1024 * 2);
  u16* ctx = qb;  // reuse: query-bf16 dead after Q projection

  // inputs -> bf16
  k_f32_to_bf16<<<4096, 256, 0, stream>>>(query, qb, 1048576);
  k_f32_to_bf16<<<4096, 256, 0, stream>>>(key,   kb, 1048576);
  k_f32_to_bf16<<<4096, 256, 0, stream>>>(value, vb, 1048576);

  // weights -> Bt (NxK) bf16.  Wt[h*64+k][d] = W[h][d][k]
  k_transpose_bf16<<<dim3(16, 1, 16), 256, 0, stream>>>(Wq, 1, wtq, 64, 1024, 16, 65536L, 65536L * 16);
  k_transpose_bf16<<<dim3(16, 1, 16), 256, 0, stream>>>(Wk, 1, wtk, 64, 1024, 16, 65536L, 65536L * 16);
  k_transpose_bf16<<<dim3(16, 1, 16), 256, 0, stream>>>(Wv, 1, wtv, 64, 1024, 16, 65536L, 65536L * 16);
  // out_w (K x N) -> wto (N x K)
  k_transpose_bf16<<<dim3(16, 16, 1), 256, 0, stream>>>(out_w, 1, wto, 1024, 1024, 1, 0L, 0L);

  // projections (Q scaled by 1/sqrt(64) exactly)
  k_gemm_bt<<<dim3(8, 32), 256, 0, stream>>>(qb, wtq, Qp, nullptr, nullptr, 4096, 1024, 1024, 0.125f);
  k_gemm_bt<<<dim3(8, 32), 256, 0, stream>>>(kb, wtk, Kp, nullptr, nullptr, 4096, 1024, 1024, 1.0f);
  k_gemm_bt<<<dim3(8, 32), 256, 0, stream>>>(vb, wtv, Vp, nullptr, nullptr, 4096, 1024, 1024, 1.0f);

  // V -> V^T per (b,h): Vt[bh][dim][l]
  k_transpose_bf16<<<dim3(32, 1, 32), 256, 0, stream>>>(Vp, 0, Vtb, 1024, 2048, 16, 64L, 2097152L);

  // attention
  k_flash<<<dim3(32, 32), 256, 0, stream>>>(Qp, Kp, Vtb, ctx);

  // output projection + bias -> f32
  k_gemm_bt<<<dim3(8, 32), 256, 0, stream>>>(ctx, wto, nullptr, out, out_b, 4096, 1024, 1024, 1.0f);
}

// Round 2
// 315.971 us; speedup vs baseline: 1.2151x; 1.2151x over previous
//
#include <hip/hip_runtime.h>
#include <cstdint>

typedef uint16_t u16;
typedef __attribute__((ext_vector_type(8))) short bf16x8;
typedef __attribute__((ext_vector_type(4))) short bf16x4;
typedef __attribute__((ext_vector_type(4))) float f32x4;

// 0.125 * log2(e): folded into Q projection so softmax is exp2(s) directly.
#define QSCALE 0.18033688011112042f

__device__ __forceinline__ u16 f2bf(float x) {
  union { float f; uint32_t u; } v; v.f = x;
  uint32_t r = (v.u + 0x7fffu + ((v.u >> 16) & 1u)) >> 16;
  return (u16)r;
}

// async global->LDS, 16B per lane. LDS dest is wave-uniform base + lane*16.
__device__ __forceinline__ void async16(void* lds, const void* g) {
  __builtin_amdgcn_global_load_lds((const __attribute__((address_space(1))) void*)g,
                                   (__attribute__((address_space(3))) void*)lds, 16, 0, 0);
}

// ---------------- elementwise f32 -> bf16 ----------------
__global__ __launch_bounds__(256) void k_f32_to_bf16(const float* __restrict__ in,
                                                     u16* __restrict__ out, int n4) {
  int i = blockIdx.x * 256 + threadIdx.x;
  if (i < n4) {
    float4 v = ((const float4*)in)[i];
    bf16x4 o;
    o[0] = (short)f2bf(v.x); o[1] = (short)f2bf(v.y);
    o[2] = (short)f2bf(v.z); o[3] = (short)f2bf(v.w);
    *(bf16x4*)(out + (size_t)i * 4) = o;
  }
}

// ---------------- tiled transpose -> bf16 ----------------
__global__ __launch_bounds__(256) void k_transpose_bf16(const void* __restrict__ in,
                                                        int in_is_f32, u16* __restrict__ out,
                                                        int rstride, int R, int sph,
                                                        long slab_lo, long slab_hi) {
  __shared__ u16 tile[64 * 72];
  const int t = threadIdx.x;
  const long z = blockIdx.z;
  const long in_base = (z / sph) * slab_hi + (z % sph) * slab_lo;
  const long out_base = z * (long)R * (long)(gridDim.y * 64);
  const int r0 = blockIdx.x * 64, c0 = blockIdx.y * 64;
  for (int e = t; e < 4096; e += 256) {
    int rr = e >> 6, cc = e & 63;
    long src = in_base + (long)(r0 + rr) * rstride + c0 + cc;
    u16 w = in_is_f32 ? f2bf(((const float*)in)[src]) : ((const u16*)in)[src];
    tile[rr * 72 + cc] = w;
  }
  __syncthreads();
  for (int s = t; s < 512; s += 256) {
    int cc = s >> 3, r8 = (s & 7) << 3;
    bf16x8 p;
    #pragma unroll
    for (int j = 0; j < 8; ++j) p[j] = (short)tile[(r8 + j) * 72 + cc];
    *(bf16x8*)(out + out_base + (long)(c0 + cc) * R + r0 + r8) = p;
  }
}

// ---------------- fused QKV GEMM: 128x128 tile, grid (8,32,3) ----------------
// z selects {A,Bt,C,scale}. C bf16 = (A*Bt^T)*scale. M=4096,N=1024,K=1024.
__global__ __launch_bounds__(256) void k_gemm_qkv(const u16* __restrict__ A0,
                                                  const u16* __restrict__ B0,
                                                  u16* __restrict__ C0, float scale0) {
  __shared__ __align__(16) u16 As[128 * 32];
  __shared__ __align__(16) u16 Bs[128 * 32];
  const int z = blockIdx.z;
  const u16* A = A0 + (long)z * 4194304;
  const u16* Bt = B0 + (long)z * 1048576;
  u16* C = C0 + (long)z * 4194304;
  const float scale = z ? 1.0f : scale0;
  const int t = threadIdx.x, lane = t & 63, quad = lane >> 4, l16 = lane & 15;
  const int wave = t >> 6, wy = wave >> 1, wx = wave & 1;
  const int m0 = blockIdx.y * 128, n0 = blockIdx.x * 128;
  const int wbase = t & 192;
  f32x4 acc[4][4] = {};
  for (int k0 = 0; k0 < 1024; k0 += 32) {
    __syncthreads();
    #pragma unroll
    for (int i = 0; i < 2; ++i) {
      int sb = i * 256 + wbase;
      int s = sb + lane;
      int row = s >> 2, c = s & 3;
      async16(As + sb * 8, A + (long)(m0 + row) * 1024 + k0 + c * 8);
      async16(Bs + sb * 8, Bt + (long)(n0 + row) * 1024 + k0 + c * 8);
    }
    __syncthreads();
    bf16x8 af[4], bfr[4];
    #pragma unroll
    for (int mt = 0; mt < 4; ++mt)
      af[mt] = *(const bf16x8*)(As + (wy * 64 + mt * 16 + l16) * 32 + quad * 8);
    #pragma unroll
    for (int nt = 0; nt < 4; ++nt)
      bfr[nt] = *(const bf16x8*)(Bs + (wx * 64 + nt * 16 + l16) * 32 + quad * 8);
    #pragma unroll
    for (int mt = 0; mt < 4; ++mt)
      #pragma unroll
      for (int nt = 0; nt < 4; ++nt)
        acc[mt][nt] = __builtin_amdgcn_mfma_f32_16x16x32_bf16(af[mt], bfr[nt], acc[mt][nt], 0, 0, 0);
  }
  #pragma unroll
  for (int mt = 0; mt < 4; ++mt)
    #pragma unroll
    for (int nt = 0; nt < 4; ++nt) {
      int col = n0 + wx * 64 + nt * 16 + l16;
      #pragma unroll
      for (int r = 0; r < 4; ++r) {
        int row = m0 + wy * 64 + mt * 16 + quad * 4 + r;
        C[(long)row * 1024 + col] = f2bf(acc[mt][nt][r] * scale);
      }
    }
}

// ---------------- out-proj GEMM: 128x64 tile, grid (16,32), f32 out + bias --
__global__ __launch_bounds__(256) void k_gemm_out(const u16* __restrict__ A,
                                                  const u16* __restrict__ Bt,
                                                  float* __restrict__ C,
                                                  const float* __restrict__ bias) {
  __shared__ __align__(16) u16 As[128 * 32];
  __shared__ __align__(16) u16 Bs[64 * 32];
  const int t = threadIdx.x, lane = t & 63, quad = lane >> 4, l16 = lane & 15;
  const int wave = t >> 6;
  const int m0 = blockIdx.y * 128, n0 = blockIdx.x * 64;
  const int wbase = t & 192;
  f32x4 acc[2][4] = {};
  for (int k0 = 0; k0 < 1024; k0 += 32) {
    __syncthreads();
    #pragma unroll
    for (int i = 0; i < 2; ++i) {
      int sb = i * 256 + wbase;
      int s = sb + lane;
      int row = s >> 2, c = s & 3;
      async16(As + sb * 8, A + (long)(m0 + row) * 1024 + k0 + c * 8);
    }
    {
      int s = t;
      int row = s >> 2, c = s & 3;
      async16(Bs + wbase * 8, Bt + (long)(n0 + row) * 1024 + k0 + c * 8);
    }
    __syncthreads();
    bf16x8 af[2], bfr[4];
    #pragma unroll
    for (int mt = 0; mt < 2; ++mt)
      af[mt] = *(const bf16x8*)(As + (wave * 32 + mt * 16 + l16) * 32 + quad * 8);
    #pragma unroll
    for (int nt = 0; nt < 4; ++nt)
      bfr[nt] = *(const bf16x8*)(Bs + (nt * 16 + l16) * 32 + quad * 8);
    #pragma unroll
    for (int mt = 0; mt < 2; ++mt)
      #pragma unroll
      for (int nt = 0; nt < 4; ++nt)
        acc[mt][nt] = __builtin_amdgcn_mfma_f32_16x16x32_bf16(af[mt], bfr[nt], acc[mt][nt], 0, 0, 0);
  }
  #pragma unroll
  for (int mt = 0; mt < 2; ++mt)
    #pragma unroll
    for (int nt = 0; nt < 4; ++nt) {
      int col = n0 + nt * 16 + l16;
      #pragma unroll
      for (int r = 0; r < 4; ++r) {
        int row = m0 + wave * 32 + mt * 16 + quad * 4 + r;
        C[(long)row * 1024 + col] = acc[mt][nt][r] + bias[col];
      }
    }
}

// ---------------- flash attention: no-max softmax, 32 q-rows/wave ----------
// Qp (B,L,H,64) bf16 pre-scaled by 0.125*log2(e). Kp (B,L,H,64). Vt (B*H,64,L).
// ctx out (B,L,H,64) bf16 normalized.
__global__ __launch_bounds__(256) void k_flash(const u16* __restrict__ Qp,
                                               const u16* __restrict__ Kp,
                                               const u16* __restrict__ Vt,
                                               u16* __restrict__ ctx) {
  __shared__ __align__(16) u16 qs[128 * 64];
  __shared__ __align__(16) u16 ks[64 * 64];
  __shared__ __align__(16) u16 vs[64 * 64];
  __shared__ __align__(16) u16 pt[4 * 64 * 34];  // per-wave P^T, row stride 34 u16
  const int t = threadIdx.x, lane = t & 63, quad = lane >> 4, l16 = lane & 15;
  const int wave = t >> 6, wbase = t & 192;
  const int bh = blockIdx.x, b = bh >> 4, h = bh & 15;
  const int q0 = blockIdx.y * 128;

  // stage Q tile (128 x 64), XOR-swizzled chunks
  {
    long gq = (long)(b * 2048 + q0) * 1024 + h * 64;
    #pragma unroll
    for (int i = 0; i < 4; ++i) {
      int sb = i * 256 + wbase, s = sb + lane;
      int row = s >> 3, pos = s & 7, c = pos ^ (row & 7);
      async16(qs + sb * 8, Qp + gq + (long)row * 1024 + c * 8);
    }
  }
  __syncthreads();
  bf16x8 qf[2][2];
  #pragma unroll
  for (int msub = 0; msub < 2; ++msub)
    #pragma unroll
    for (int kh = 0; kh < 2; ++kh) {
      int m = wave * 32 + msub * 16 + l16;
      int pos = (kh * 4 + quad) ^ (m & 7);
      qf[msub][kh] = *(const bf16x8*)(qs + m * 64 + pos * 8);
    }

  float lsum[2][4] = {};
  f32x4 o[2][4] = {};
  u16* ptw = pt + wave * 2176;

  for (int kt = 0; kt < 32; ++kt) {
    const int kv0 = kt * 64;
    __syncthreads();
    {
      long gk = (long)(b * 2048 + kv0) * 1024 + h * 64;
      long gv = (long)bh * 131072 + kv0;
      #pragma unroll
      for (int i = 0; i < 2; ++i) {
        int sb = i * 256 + wbase, s = sb + lane;
        int row = s >> 3, pos = s & 7, c = pos ^ (row & 7);
        async16(ks + sb * 8, Kp + gk + (long)row * 1024 + c * 8);
        async16(vs + sb * 8, Vt + gv + (long)row * 2048 + c * 8);
      }
    }
    __syncthreads();

    // K fragments (shared across both m-subtiles)
    bf16x8 kf[4][2];
    #pragma unroll
    for (int nt = 0; nt < 4; ++nt)
      #pragma unroll
      for (int kh = 0; kh < 2; ++kh) {
        int rowk = nt * 16 + l16;
        int pos = (kh * 4 + quad) ^ (rowk & 7);
        kf[nt][kh] = *(const bf16x8*)(ks + rowk * 64 + pos * 8);
      }

    // S = Q @ K^T ; p = exp2(S) ; accumulate l ; write P^T to LDS
    #pragma unroll
    for (int msub = 0; msub < 2; ++msub)
      #pragma unroll
      for (int nt = 0; nt < 4; ++nt) {
        f32x4 a = {};
        #pragma unroll
        for (int kh = 0; kh < 2; ++kh)
          a = __builtin_amdgcn_mfma_f32_16x16x32_bf16(qf[msub][kh], kf[nt][kh], a, 0, 0, 0);
        bf16x4 pk;
        #pragma unroll
        for (int r = 0; r < 4; ++r) {
          float e = __builtin_amdgcn_exp2f(a[r]);
          lsum[msub][r] += e;
          pk[r] = (short)f2bf(e);
        }
        *(bf16x4*)(ptw + (nt * 16 + l16) * 34 + msub * 16 + quad * 4) = pk;
      }

    // V fragments
    bf16x8 vf[4][2];
    #pragma unroll
    for (int nt = 0; nt < 4; ++nt)
      #pragma unroll
      for (int kh = 0; kh < 2; ++kh) {
        int rowv = nt * 16 + l16;
        int pos = (kh * 4 + quad) ^ (rowv & 7);
        vf[nt][kh] = *(const bf16x8*)(vs + rowv * 64 + pos * 8);
      }

    // O += P @ V
    #pragma unroll
    for (int msub = 0; msub < 2; ++msub)
      #pragma unroll
      for (int kh = 0; kh < 2; ++kh) {
        bf16x8 pa;
        #pragma unroll
        for (int j = 0; j < 8; ++j)
          pa[j] = (short)ptw[(kh * 32 + quad * 8 + j) * 34 + msub * 16 + l16];
        #pragma unroll
        for (int nt = 0; nt < 4; ++nt)
          o[msub][nt] = __builtin_amdgcn_mfma_f32_16x16x32_bf16(pa, vf[nt][kh], o[msub][nt], 0, 0, 0);
      }
  }

  // final l reduction across the 16 kv-lanes, then normalize + write
  #pragma unroll
  for (int msub = 0; msub < 2; ++msub)
    #pragma unroll
    for (int r = 0; r < 4; ++r) {
      float l = lsum[msub][r];
      #pragma unroll
      for (int d = 1; d < 16; d <<= 1) l += __shfl_xor(l, d);
      lsum[msub][r] = 1.0f / l;
    }
  #pragma unroll
  for (int msub = 0; msub < 2; ++msub)
    #pragma unroll
    for (int nt = 0; nt < 4; ++nt)
      #pragma unroll
      for (int r = 0; r < 4; ++r) {
        int q = q0 + wave * 32 + msub * 16 + quad * 4 + r;
        long idx = (long)(b * 2048 + q) * 1024 + h * 64 + nt * 16 + l16;
        ctx[idx] = f2bf(o[msub][nt][r] * lsum[msub][r]);
      }
}

extern "C" void kernel_launch(void* const* d_in, const int* in_sizes, int n_in,
                              void* d_out, int out_size, void* d_ws, size_t ws_size,
                              hipStream_t stream) {
  const float* query = (const float*)d_in[0];
  const float* key   = (const float*)d_in[1];
  const float* value = (const float*)d_in[2];
  const float* Wq    = (const float*)d_in[3];
  const float* Wk    = (const float*)d_in[4];
  const float* Wv    = (const float*)d_in[5];
  const float* out_w = (const float*)d_in[6];
  const float* out_b = (const float*)d_in[7];
  // d_in[8] = coupling: unused — per-head scalar bias is softmax-invariant.
  float* out = (float*)d_out;

  char* ws = (char*)d_ws;
  size_t off = 0;
  auto alloc = [&](size_t bytes) {
    void* p = ws + off;
    off += (bytes + 255) & ~(size_t)255;
    return p;
  };
  // NOTE: qb,kb,vb contiguous; wtq,wtk,wtv contiguous; Qp,Kp,Vp contiguous —
  // k_gemm_qkv indexes them by z-stride.
  u16* qb  = (u16*)alloc(4096L * 1024 * 2);
  u16* kb  = (u16*)alloc(4096L * 1024 * 2);
  u16* vb  = (u16*)alloc(4096L * 1024 * 2);
  u16* wtq = (u16*)alloc(1024L * 1024 * 2);
  u16* wtk = (u16*)alloc(1024L * 1024 * 2);
  u16* wtv = (u16*)alloc(1024L * 1024 * 2);
  u16* wto = (u16*)alloc(1024L * 1024 * 2);
  u16* Qp  = (u16*)alloc(4096L * 1024 * 2);
  u16* Kp  = (u16*)alloc(4096L * 1024 * 2);
  u16* Vp  = (u16*)alloc(4096L * 1024 * 2);
  u16* Vtb = (u16*)alloc(4096L * 1024 * 2);
  u16* ctx = qb;  // reuse: query-bf16 dead after Q projection
  (void)kb; (void)vb; (void)wtk; (void)wtv; (void)Kp; (void)Vp;

  // inputs -> bf16
  k_f32_to_bf16<<<4096, 256, 0, stream>>>(query, qb, 1048576);
  k_f32_to_bf16<<<4096, 256, 0, stream>>>(key,   kb, 1048576);
  k_f32_to_bf16<<<4096, 256, 0, stream>>>(value, vb, 1048576);

  // weights -> Bt (NxK) bf16.  Wt[h*64+k][d] = W[h][d][k]
  k_transpose_bf16<<<dim3(16, 1, 16), 256, 0, stream>>>(Wq, 1, wtq, 64, 1024, 16, 65536L, 65536L * 16);
  k_transpose_bf16<<<dim3(16, 1, 16), 256, 0, stream>>>(Wk, 1, wtk, 64, 1024, 16, 65536L, 65536L * 16);
  k_transpose_bf16<<<dim3(16, 1, 16), 256, 0, stream>>>(Wv, 1, wtv, 64, 1024, 16, 65536L, 65536L * 16);
  // out_w (K x N) -> wto (N x K)
  k_transpose_bf16<<<dim3(16, 16, 1), 256, 0, stream>>>(out_w, 1, wto, 1024, 1024, 1, 0L, 0L);

  // fused Q,K,V projections (Q pre-scaled by 0.125*log2(e))
  k_gemm_qkv<<<dim3(8, 32, 3), 256, 0, stream>>>(qb, wtq, Qp, QSCALE);

  // V -> V^T per (b,h): Vt[bh][dim][l]
  k_transpose_bf16<<<dim3(32, 1, 32), 256, 0, stream>>>(Vp, 0, Vtb, 1024, 2048, 16, 64L, 2097152L);

  // attention
  k_flash<<<dim3(32, 16), 256, 0, stream>>>(Qp, Kp, Vtb, ctx);

  // output projection + bias -> f32
  k_gemm_out<<<dim3(16, 32), 256, 0, stream>>>(ctx, wto, out, out_b);
}

// Round 3
// 304.541 us; speedup vs baseline: 1.2607x; 1.0375x over previous
//
#include <hip/hip_runtime.h>
#include <cstdint>

typedef uint16_t u16;
typedef __attribute__((ext_vector_type(8))) short bf16x8;
typedef __attribute__((ext_vector_type(4))) short bf16x4;
typedef __attribute__((ext_vector_type(4))) float f32x4;

// 0.125 * log2(e): folded into Q projection so softmax is exp2(s) directly.
#define QSCALE 0.18033688011112042f

struct Ptr3 { const float* a; const float* b; const float* c; };

__device__ __forceinline__ u16 f2bf(float x) {
  union { float f; uint32_t u; } v; v.f = x;
  uint32_t r = (v.u + 0x7fffu + ((v.u >> 16) & 1u)) >> 16;
  return (u16)r;
}

// async global->LDS, 16B per lane. LDS dest is wave-uniform base + lane*16.
__device__ __forceinline__ void async16(void* lds, const void* g) {
  __builtin_amdgcn_global_load_lds((const __attribute__((address_space(1))) void*)g,
                                   (__attribute__((address_space(3))) void*)lds, 16, 0, 0);
}

// ---------------- fused elementwise f32 -> bf16 (3 tensors) ----------------
__global__ __launch_bounds__(256) void k_cast3(Ptr3 in, u16* __restrict__ out) {
  const int z = blockIdx.y;
  const float* p = z == 0 ? in.a : (z == 1 ? in.b : in.c);
  int i = blockIdx.x * 256 + threadIdx.x;
  float4 v = ((const float4*)p)[i];
  bf16x4 o;
  o[0] = (short)f2bf(v.x); o[1] = (short)f2bf(v.y);
  o[2] = (short)f2bf(v.z); o[3] = (short)f2bf(v.w);
  *(bf16x4*)(out + (long)z * 4194304 + (long)i * 4) = o;
}

// ---------------- fused Wq/Wk/Wv transpose: grid (16,1,48) ----------------
// W[h][d][k] (f32, 1024x64 per head) -> wt[w][h*64+k][d] (bf16)
__global__ __launch_bounds__(256) void k_transpose_w(Ptr3 w, u16* __restrict__ out) {
  __shared__ u16 tile[64 * 72];
  const int t = threadIdx.x;
  const int z = blockIdx.z;
  const float* in = (z < 16) ? w.a : (z < 32 ? w.b : w.c);
  const long in_base = (long)(z & 15) * 65536;
  const long out_base = (long)z * 65536;
  const int r0 = blockIdx.x * 64;
  for (int e = t; e < 4096; e += 256) {
    int rr = e >> 6, cc = e & 63;
    tile[rr * 72 + cc] = f2bf(in[in_base + (long)(r0 + rr) * 64 + cc]);
  }
  __syncthreads();
  for (int s = t; s < 512; s += 256) {
    int cc = s >> 3, r8 = (s & 7) << 3;
    bf16x8 p;
    #pragma unroll
    for (int j = 0; j < 8; ++j) p[j] = (short)tile[(r8 + j) * 72 + cc];
    *(bf16x8*)(out + out_base + (long)cc * 1024 + r0 + r8) = p;
  }
}

// ---------------- generic tiled transpose -> bf16 ----------------
__global__ __launch_bounds__(256) void k_transpose_bf16(const void* __restrict__ in,
                                                        int in_is_f32, u16* __restrict__ out,
                                                        int rstride, int R, int sph,
                                                        long slab_lo, long slab_hi) {
  __shared__ u16 tile[64 * 72];
  const int t = threadIdx.x;
  const long z = blockIdx.z;
  const long in_base = (z / sph) * slab_hi + (z % sph) * slab_lo;
  const long out_base = z * (long)R * (long)(gridDim.y * 64);
  const int r0 = blockIdx.x * 64, c0 = blockIdx.y * 64;
  for (int e = t; e < 4096; e += 256) {
    int rr = e >> 6, cc = e & 63;
    long src = in_base + (long)(r0 + rr) * rstride + c0 + cc;
    u16 w = in_is_f32 ? f2bf(((const float*)in)[src]) : ((const u16*)in)[src];
    tile[rr * 72 + cc] = w;
  }
  __syncthreads();
  for (int s = t; s < 512; s += 256) {
    int cc = s >> 3, r8 = (s & 7) << 3;
    bf16x8 p;
    #pragma unroll
    for (int j = 0; j < 8; ++j) p[j] = (short)tile[(r8 + j) * 72 + cc];
    *(bf16x8*)(out + out_base + (long)(c0 + cc) * R + r0 + r8) = p;
  }
}

// ---------------- fused QKV GEMM: 128x128 tile, grid (8,32,3) ----------------
__global__ __launch_bounds__(256) void k_gemm_qkv(const u16* __restrict__ A0,
                                                  const u16* __restrict__ B0,
                                                  u16* __restrict__ C0, float scale0) {
  __shared__ __align__(16) u16 As[128 * 32];
  __shared__ __align__(16) u16 Bs[128 * 32];
  const int z = blockIdx.z;
  const u16* A = A0 + (long)z * 4194304;
  const u16* Bt = B0 + (long)z * 1048576;
  u16* C = C0 + (long)z * 4194304;
  const float scale = z ? 1.0f : scale0;
  const int t = threadIdx.x, lane = t & 63, quad = lane >> 4, l16 = lane & 15;
  const int wave = t >> 6, wy = wave >> 1, wx = wave & 1;
  const int m0 = blockIdx.y * 128, n0 = blockIdx.x * 128;
  const int wbase = t & 192;
  f32x4 acc[4][4] = {};
  for (int k0 = 0; k0 < 1024; k0 += 32) {
    __syncthreads();
    #pragma unroll
    for (int i = 0; i < 2; ++i) {
      int sb = i * 256 + wbase;
      int s = sb + lane;
      int row = s >> 2, c = s & 3;
      async16(As + sb * 8, A + (long)(m0 + row) * 1024 + k0 + c * 8);
      async16(Bs + sb * 8, Bt + (long)(n0 + row) * 1024 + k0 + c * 8);
    }
    __syncthreads();
    bf16x8 af[4], bfr[4];
    #pragma unroll
    for (int mt = 0; mt < 4; ++mt)
      af[mt] = *(const bf16x8*)(As + (wy * 64 + mt * 16 + l16) * 32 + quad * 8);
    #pragma unroll
    for (int nt = 0; nt < 4; ++nt)
      bfr[nt] = *(const bf16x8*)(Bs + (wx * 64 + nt * 16 + l16) * 32 + quad * 8);
    #pragma unroll
    for (int mt = 0; mt < 4; ++mt)
      #pragma unroll
      for (int nt = 0; nt < 4; ++nt)
        acc[mt][nt] = __builtin_amdgcn_mfma_f32_16x16x32_bf16(af[mt], bfr[nt], acc[mt][nt], 0, 0, 0);
  }
  #pragma unroll
  for (int mt = 0; mt < 4; ++mt)
    #pragma unroll
    for (int nt = 0; nt < 4; ++nt) {
      int col = n0 + wx * 64 + nt * 16 + l16;
      #pragma unroll
      for (int r = 0; r < 4; ++r) {
        int row = m0 + wy * 64 + mt * 16 + quad * 4 + r;
        C[(long)row * 1024 + col] = f2bf(acc[mt][nt][r] * scale);
      }
    }
}

// ---------------- out-proj GEMM: 128x64 tile, grid (16,32), f32 out + bias --
__global__ __launch_bounds__(256) void k_gemm_out(const u16* __restrict__ A,
                                                  const u16* __restrict__ Bt,
                                                  float* __restrict__ C,
                                                  const float* __restrict__ bias) {
  __shared__ __align__(16) u16 As[128 * 32];
  __shared__ __align__(16) u16 Bs[64 * 32];
  const int t = threadIdx.x, lane = t & 63, quad = lane >> 4, l16 = lane & 15;
  const int wave = t >> 6;
  const int m0 = blockIdx.y * 128, n0 = blockIdx.x * 64;
  const int wbase = t & 192;
  f32x4 acc[2][4] = {};
  for (int k0 = 0; k0 < 1024; k0 += 32) {
    __syncthreads();
    #pragma unroll
    for (int i = 0; i < 2; ++i) {
      int sb = i * 256 + wbase;
      int s = sb + lane;
      int row = s >> 2, c = s & 3;
      async16(As + sb * 8, A + (long)(m0 + row) * 1024 + k0 + c * 8);
    }
    {
      int s = t;
      int row = s >> 2, c = s & 3;
      async16(Bs + wbase * 8, Bt + (long)(n0 + row) * 1024 + k0 + c * 8);
    }
    __syncthreads();
    bf16x8 af[2], bfr[4];
    #pragma unroll
    for (int mt = 0; mt < 2; ++mt)
      af[mt] = *(const bf16x8*)(As + (wave * 32 + mt * 16 + l16) * 32 + quad * 8);
    #pragma unroll
    for (int nt = 0; nt < 4; ++nt)
      bfr[nt] = *(const bf16x8*)(Bs + (nt * 16 + l16) * 32 + quad * 8);
    #pragma unroll
    for (int mt = 0; mt < 2; ++mt)
      #pragma unroll
      for (int nt = 0; nt < 4; ++nt)
        acc[mt][nt] = __builtin_amdgcn_mfma_f32_16x16x32_bf16(af[mt], bfr[nt], acc[mt][nt], 0, 0, 0);
  }
  #pragma unroll
  for (int mt = 0; mt < 2; ++mt)
    #pragma unroll
    for (int nt = 0; nt < 4; ++nt) {
      int col = n0 + nt * 16 + l16;
      #pragma unroll
      for (int r = 0; r < 4; ++r) {
        int row = m0 + wave * 32 + mt * 16 + quad * 4 + r;
        C[(long)row * 1024 + col] = acc[mt][nt][r] + bias[col];
      }
    }
}

// ---------------- flash attention: no-max softmax, K/V prefetch dbuf -------
// Qp (B,L,H,64) bf16 pre-scaled by 0.125*log2(e). Kp (B,L,H,64). Vt (B*H,64,L).
// ctx out (B,L,H,64) bf16 normalized.
__global__ __launch_bounds__(256) void k_flash(const u16* __restrict__ Qp,
                                               const u16* __restrict__ Kp,
                                               const u16* __restrict__ Vt,
                                               u16* __restrict__ ctx) {
  __shared__ __align__(16) u16 qs[128 * 64];
  __shared__ __align__(16) u16 ks[2][64 * 64];
  __shared__ __align__(16) u16 vs[2][64 * 64];
  __shared__ __align__(16) u16 pt[4 * 64 * 34];  // per-wave P^T, row stride 34 u16
  const int t = threadIdx.x, lane = t & 63, quad = lane >> 4, l16 = lane & 15;
  const int wave = t >> 6, wbase = t & 192;
  const int bh = blockIdx.x, b = bh >> 4, h = bh & 15;
  const int q0 = blockIdx.y * 128;
  const long gkbase = (long)b * 2097152 + h * 64;
  const long gvbase = (long)bh * 131072;

  // XOR-swizzled staging: LDS chunk pos p of row holds global chunk p^(row&7)
  auto stageKV = [&](int kt, int buf) {
    const int kv0 = kt * 64;
    #pragma unroll
    for (int i = 0; i < 2; ++i) {
      int sb = i * 256 + wbase, s = sb + lane;
      int row = s >> 3, pos = s & 7, c = pos ^ (row & 7);
      async16(ks[buf] + sb * 8, Kp + gkbase + (long)(kv0 + row) * 1024 + c * 8);
      async16(vs[buf] + sb * 8, Vt + gvbase + kv0 + (long)row * 2048 + c * 8);
    }
  };

  // stage Q tile (128 x 64) + first K/V tile, one barrier
  {
    long gq = (long)(b * 2048 + q0) * 1024 + h * 64;
    #pragma unroll
    for (int i = 0; i < 4; ++i) {
      int sb = i * 256 + wbase, s = sb + lane;
      int row = s >> 3, pos = s & 7, c = pos ^ (row & 7);
      async16(qs + sb * 8, Qp + gq + (long)row * 1024 + c * 8);
    }
  }
  stageKV(0, 0);
  __syncthreads();

  bf16x8 qf[2][2];
  #pragma unroll
  for (int msub = 0; msub < 2; ++msub)
    #pragma unroll
    for (int kh = 0; kh < 2; ++kh) {
      int m = wave * 32 + msub * 16 + l16;
      int pos = (kh * 4 + quad) ^ (m & 7);
      qf[msub][kh] = *(const bf16x8*)(qs + m * 64 + pos * 8);
    }

  float lsum[2][4] = {};
  f32x4 o[2][4] = {};
  u16* ptw = pt + wave * 2176;

  for (int kt = 0; kt < 32; ++kt) {
    // prefetch next tile; in flight during this iteration's compute,
    // drained by the barrier at the end of the iteration.
    if (kt < 31) stageKV(kt + 1, (kt + 1) & 1);
    const u16* ksb = ks[kt & 1];
    const u16* vsb = vs[kt & 1];

    // K fragments (shared across both m-subtiles)
    bf16x8 kf[4][2];
    #pragma unroll
    for (int nt = 0; nt < 4; ++nt)
      #pragma unroll
      for (int kh = 0; kh < 2; ++kh) {
        int rowk = nt * 16 + l16;
        int pos = (kh * 4 + quad) ^ (rowk & 7);
        kf[nt][kh] = *(const bf16x8*)(ksb + rowk * 64 + pos * 8);
      }

    // S = Q @ K^T ; p = exp2(S) ; accumulate l ; write P^T to LDS
    #pragma unroll
    for (int msub = 0; msub < 2; ++msub)
      #pragma unroll
      for (int nt = 0; nt < 4; ++nt) {
        f32x4 a = {};
        #pragma unroll
        for (int kh = 0; kh < 2; ++kh)
          a = __builtin_amdgcn_mfma_f32_16x16x32_bf16(qf[msub][kh], kf[nt][kh], a, 0, 0, 0);
        bf16x4 pk;
        #pragma unroll
        for (int r = 0; r < 4; ++r) {
          float e = __builtin_amdgcn_exp2f(a[r]);
          lsum[msub][r] += e;
          pk[r] = (short)f2bf(e);
        }
        *(bf16x4*)(ptw + (nt * 16 + l16) * 34 + msub * 16 + quad * 4) = pk;
      }

    // V fragments
    bf16x8 vf[4][2];
    #pragma unroll
    for (int nt = 0; nt < 4; ++nt)
      #pragma unroll
      for (int kh = 0; kh < 2; ++kh) {
        int rowv = nt * 16 + l16;
        int pos = (kh * 4 + quad) ^ (rowv & 7);
        vf[nt][kh] = *(const bf16x8*)(vsb + rowv * 64 + pos * 8);
      }

    // O += P @ V
    #pragma unroll
    for (int msub = 0; msub < 2; ++msub)
      #pragma unroll
      for (int kh = 0; kh < 2; ++kh) {
        bf16x8 pa;
        #pragma unroll
        for (int j = 0; j < 8; ++j)
          pa[j] = (short)ptw[(kh * 32 + quad * 8 + j) * 34 + msub * 16 + l16];
        #pragma unroll
        for (int nt = 0; nt < 4; ++nt)
          o[msub][nt] = __builtin_amdgcn_mfma_f32_16x16x32_bf16(pa, vf[nt][kh], o[msub][nt], 0, 0, 0);
      }

    __syncthreads();  // drains prefetch (full compute phase in flight) + guards buffer reuse
  }

  // final l reduction across the 16 kv-lanes, then normalize + write
  #pragma unroll
  for (int msub = 0; msub < 2; ++msub)
    #pragma unroll
    for (int r = 0; r < 4; ++r) {
      float l = lsum[msub][r];
      #pragma unroll
      for (int d = 1; d < 16; d <<= 1) l += __shfl_xor(l, d);
      lsum[msub][r] = 1.0f / l;
    }
  #pragma unroll
  for (int msub = 0; msub < 2; ++msub)
    #pragma unroll
    for (int nt = 0; nt < 4; ++nt)
      #pragma unroll
      for (int r = 0; r < 4; ++r) {
        int q = q0 + wave * 32 + msub * 16 + quad * 4 + r;
        long idx = (long)(b * 2048 + q) * 1024 + h * 64 + nt * 16 + l16;
        ctx[idx] = f2bf(o[msub][nt][r] * lsum[msub][r]);
      }
}

extern "C" void kernel_launch(void* const* d_in, const int* in_sizes, int n_in,
                              void* d_out, int out_size, void* d_ws, size_t ws_size,
                              hipStream_t stream) {
  const float* query = (const float*)d_in[0];
  const float* key   = (const float*)d_in[1];
  const float* value = (const float*)d_in[2];
  const float* Wq    = (const float*)d_in[3];
  const float* Wk    = (const float*)d_in[4];
  const float* Wv    = (const float*)d_in[5];
  const float* out_w = (const float*)d_in[6];
  const float* out_b = (const float*)d_in[7];
  // d_in[8] = coupling: unused — per-head scalar bias is softmax-invariant.
  float* out = (float*)d_out;

  char* ws = (char*)d_ws;
  size_t off = 0;
  auto alloc = [&](size_t bytes) {
    void* p = ws + off;
    off += (bytes + 255) & ~(size_t)255;
    return p;
  };
  // qb,kb,vb contiguous; wtq,wtk,wtv contiguous; Qp,Kp,Vp contiguous —
  // k_cast3 / k_transpose_w / k_gemm_qkv index them by z-stride.
  u16* qb  = (u16*)alloc(4096L * 1024 * 2);
  u16* kb  = (u16*)alloc(4096L * 1024 * 2);
  u16* vb  = (u16*)alloc(4096L * 1024 * 2);
  u16* wtq = (u16*)alloc(1024L * 1024 * 2);
  u16* wtk = (u16*)alloc(1024L * 1024 * 2);
  u16* wtv = (u16*)alloc(1024L * 1024 * 2);
  u16* wto = (u16*)alloc(1024L * 1024 * 2);
  u16* Qp  = (u16*)alloc(4096L * 1024 * 2);
  u16* Kp  = (u16*)alloc(4096L * 1024 * 2);
  u16* Vp  = (u16*)alloc(4096L * 1024 * 2);
  u16* Vtb = (u16*)alloc(4096L * 1024 * 2);
  u16* ctx = qb;  // reuse: query-bf16 dead after Q projection
  (void)kb; (void)vb; (void)wtk; (void)wtv; (void)Kp; (void)Vp;

  // inputs -> bf16 (fused, grid.y selects tensor)
  k_cast3<<<dim3(4096, 3), 256, 0, stream>>>(Ptr3{query, key, value}, qb);

  // Wq/Wk/Wv -> Bt (NxK) bf16 (fused).  wt[w][h*64+k][d] = W[w][h][d][k]
  k_transpose_w<<<dim3(16, 1, 48), 256, 0, stream>>>(Ptr3{Wq, Wk, Wv}, wtq);
  // out_w (K x N) -> wto (N x K)
  k_transpose_bf16<<<dim3(16, 16, 1), 256, 0, stream>>>(out_w, 1, wto, 1024, 1024, 1, 0L, 0L);

  // fused Q,K,V projections (Q pre-scaled by 0.125*log2(e))
  k_gemm_qkv<<<dim3(8, 32, 3), 256, 0, stream>>>(qb, wtq, Qp, QSCALE);

  // V -> V^T per (b,h): Vt[bh][dim][l]
  k_transpose_bf16<<<dim3(32, 1, 32), 256, 0, stream>>>(Vp, 0, Vtb, 1024, 2048, 16, 64L, 2097152L);

  // attention
  k_flash<<<dim3(32, 16), 256, 0, stream>>>(Qp, Kp, Vtb, ctx);

  // output projection + bias -> f32
  k_gemm_out<<<dim3(16, 32), 256, 0, stream>>>(ctx, wto, out, out_b);
}

// Round 4
// 250.407 us; speedup vs baseline: 1.5333x; 1.2162x over previous
//
#include <hip/hip_runtime.h>
#include <cstdint>

typedef uint16_t u16;
typedef __attribute__((ext_vector_type(8))) short bf16x8;
typedef __attribute__((ext_vector_type(4))) short bf16x4;
typedef __attribute__((ext_vector_type(4))) float f32x4;

// 0.125 * log2(e): folded into Q projection so softmax is exp2(s) directly.
#define QSCALE 0.18033688011112042f

struct Ptr3 { const float* a; const float* b; const float* c; };

__device__ __forceinline__ u16 f2bf(float x) {
  union { float f; uint32_t u; } v; v.f = x;
  uint32_t r = (v.u + 0x7fffu + ((v.u >> 16) & 1u)) >> 16;
  return (u16)r;
}

// async global->LDS, 16B per lane. LDS dest is wave-uniform base + lane*16.
__device__ __forceinline__ void async16(void* lds, const void* g) {
  __builtin_amdgcn_global_load_lds((const __attribute__((address_space(1))) void*)g,
                                   (__attribute__((address_space(3))) void*)lds, 16, 0, 0);
}

// ---------------- fused elementwise f32 -> bf16 (3 tensors) ----------------
__global__ __launch_bounds__(256) void k_cast3(Ptr3 in, u16* __restrict__ out) {
  const int z = blockIdx.y;
  const float* p = z == 0 ? in.a : (z == 1 ? in.b : in.c);
  int i = blockIdx.x * 256 + threadIdx.x;
  float4 v = ((const float4*)p)[i];
  bf16x4 o;
  o[0] = (short)f2bf(v.x); o[1] = (short)f2bf(v.y);
  o[2] = (short)f2bf(v.z); o[3] = (short)f2bf(v.w);
  *(bf16x4*)(out + (long)z * 4194304 + (long)i * 4) = o;
}

// ---------------- fused Wq/Wk/Wv transpose: grid (16,1,48) ----------------
// W[h][d][k] (f32, 1024x64 per head) -> wt[w][h*64+k][d] (bf16)
__global__ __launch_bounds__(256) void k_transpose_w(Ptr3 w, u16* __restrict__ out) {
  __shared__ u16 tile[64 * 72];
  const int t = threadIdx.x;
  const int z = blockIdx.z;
  const float* in = (z < 16) ? w.a : (z < 32 ? w.b : w.c);
  const long in_base = (long)(z & 15) * 65536;
  const long out_base = (long)z * 65536;
  const int r0 = blockIdx.x * 64;
  for (int e = t; e < 4096; e += 256) {
    int rr = e >> 6, cc = e & 63;
    tile[rr * 72 + cc] = f2bf(in[in_base + (long)(r0 + rr) * 64 + cc]);
  }
  __syncthreads();
  for (int s = t; s < 512; s += 256) {
    int cc = s >> 3, r8 = (s & 7) << 3;
    bf16x8 p;
    #pragma unroll
    for (int j = 0; j < 8; ++j) p[j] = (short)tile[(r8 + j) * 72 + cc];
    *(bf16x8*)(out + out_base + (long)cc * 1024 + r0 + r8) = p;
  }
}

// ---------------- generic tiled transpose -> bf16 ----------------
__global__ __launch_bounds__(256) void k_transpose_bf16(const void* __restrict__ in,
                                                        int in_is_f32, u16* __restrict__ out,
                                                        int rstride, int R, int sph,
                                                        long slab_lo, long slab_hi) {
  __shared__ u16 tile[64 * 72];
  const int t = threadIdx.x;
  const long z = blockIdx.z;
  const long in_base = (z / sph) * slab_hi + (z % sph) * slab_lo;
  const long out_base = z * (long)R * (long)(gridDim.y * 64);
  const int r0 = blockIdx.x * 64, c0 = blockIdx.y * 64;
  for (int e = t; e < 4096; e += 256) {
    int rr = e >> 6, cc = e & 63;
    long src = in_base + (long)(r0 + rr) * rstride + c0 + cc;
    u16 w = in_is_f32 ? f2bf(((const float*)in)[src]) : ((const u16*)in)[src];
    tile[rr * 72 + cc] = w;
  }
  __syncthreads();
  for (int s = t; s < 512; s += 256) {
    int cc = s >> 3, r8 = (s & 7) << 3;
    bf16x8 p;
    #pragma unroll
    for (int j = 0; j < 8; ++j) p[j] = (short)tile[(r8 + j) * 72 + cc];
    *(bf16x8*)(out + out_base + (long)(c0 + cc) * R + r0 + r8) = p;
  }
}

// ---------------- fused QKV GEMM: 128x128 tile, grid (8,32,3) ----------------
__global__ __launch_bounds__(256) void k_gemm_qkv(const u16* __restrict__ A0,
                                                  const u16* __restrict__ B0,
                                                  u16* __restrict__ C0, float scale0) {
  __shared__ __align__(16) u16 As[128 * 32];
  __shared__ __align__(16) u16 Bs[128 * 32];
  const int z = blockIdx.z;
  const u16* A = A0 + (long)z * 4194304;
  const u16* Bt = B0 + (long)z * 1048576;
  u16* C = C0 + (long)z * 4194304;
  const float scale = z ? 1.0f : scale0;
  const int t = threadIdx.x, lane = t & 63, quad = lane >> 4, l16 = lane & 15;
  const int wave = t >> 6, wy = wave >> 1, wx = wave & 1;
  const int m0 = blockIdx.y * 128, n0 = blockIdx.x * 128;
  const int wbase = t & 192;
  f32x4 acc[4][4] = {};
  for (int k0 = 0; k0 < 1024; k0 += 32) {
    __syncthreads();
    #pragma unroll
    for (int i = 0; i < 2; ++i) {
      int sb = i * 256 + wbase;
      int s = sb + lane;
      int row = s >> 2, c = s & 3;
      async16(As + sb * 8, A + (long)(m0 + row) * 1024 + k0 + c * 8);
      async16(Bs + sb * 8, Bt + (long)(n0 + row) * 1024 + k0 + c * 8);
    }
    __syncthreads();
    bf16x8 af[4], bfr[4];
    #pragma unroll
    for (int mt = 0; mt < 4; ++mt)
      af[mt] = *(const bf16x8*)(As + (wy * 64 + mt * 16 + l16) * 32 + quad * 8);
    #pragma unroll
    for (int nt = 0; nt < 4; ++nt)
      bfr[nt] = *(const bf16x8*)(Bs + (wx * 64 + nt * 16 + l16) * 32 + quad * 8);
    #pragma unroll
    for (int mt = 0; mt < 4; ++mt)
      #pragma unroll
      for (int nt = 0; nt < 4; ++nt)
        acc[mt][nt] = __builtin_amdgcn_mfma_f32_16x16x32_bf16(af[mt], bfr[nt], acc[mt][nt], 0, 0, 0);
  }
  #pragma unroll
  for (int mt = 0; mt < 4; ++mt)
    #pragma unroll
    for (int nt = 0; nt < 4; ++nt) {
      int col = n0 + wx * 64 + nt * 16 + l16;
      #pragma unroll
      for (int r = 0; r < 4; ++r) {
        int row = m0 + wy * 64 + mt * 16 + quad * 4 + r;
        C[(long)row * 1024 + col] = f2bf(acc[mt][nt][r] * scale);
      }
    }
}

// ---------------- out-proj GEMM: 128x64 tile, grid (16,32), f32 out + bias --
__global__ __launch_bounds__(256) void k_gemm_out(const u16* __restrict__ A,
                                                  const u16* __restrict__ Bt,
                                                  float* __restrict__ C,
                                                  const float* __restrict__ bias) {
  __shared__ __align__(16) u16 As[128 * 32];
  __shared__ __align__(16) u16 Bs[64 * 32];
  const int t = threadIdx.x, lane = t & 63, quad = lane >> 4, l16 = lane & 15;
  const int wave = t >> 6;
  const int m0 = blockIdx.y * 128, n0 = blockIdx.x * 64;
  const int wbase = t & 192;
  f32x4 acc[2][4] = {};
  for (int k0 = 0; k0 < 1024; k0 += 32) {
    __syncthreads();
    #pragma unroll
    for (int i = 0; i < 2; ++i) {
      int sb = i * 256 + wbase;
      int s = sb + lane;
      int row = s >> 2, c = s & 3;
      async16(As + sb * 8, A + (long)(m0 + row) * 1024 + k0 + c * 8);
    }
    {
      int s = t;
      int row = s >> 2, c = s & 3;
      async16(Bs + wbase * 8, Bt + (long)(n0 + row) * 1024 + k0 + c * 8);
    }
    __syncthreads();
    bf16x8 af[2], bfr[4];
    #pragma unroll
    for (int mt = 0; mt < 2; ++mt)
      af[mt] = *(const bf16x8*)(As + (wave * 32 + mt * 16 + l16) * 32 + quad * 8);
    #pragma unroll
    for (int nt = 0; nt < 4; ++nt)
      bfr[nt] = *(const bf16x8*)(Bs + (nt * 16 + l16) * 32 + quad * 8);
    #pragma unroll
    for (int mt = 0; mt < 2; ++mt)
      #pragma unroll
      for (int nt = 0; nt < 4; ++nt)
        acc[mt][nt] = __builtin_amdgcn_mfma_f32_16x16x32_bf16(af[mt], bfr[nt], acc[mt][nt], 0, 0, 0);
  }
  #pragma unroll
  for (int mt = 0; mt < 2; ++mt)
    #pragma unroll
    for (int nt = 0; nt < 4; ++nt) {
      int col = n0 + nt * 16 + l16;
      #pragma unroll
      for (int r = 0; r < 4; ++r) {
        int row = m0 + wave * 32 + mt * 16 + quad * 4 + r;
        C[(long)row * 1024 + col] = acc[mt][nt][r] + bias[col];
      }
    }
}

// ---------------- flash attention v4 -------------------------------------
// 512 threads, q-tile 256 (32 rows/wave). K/V staged via regs + ds_write
// (padded stride-72 rows, no swizzle needed). XCD-aware: bh = blockIdx%32 so
// all q-tiles of a head share one XCD's L2 (4 heads x 512KB = 2MB < 4MiB).
// Qp (B,L,H,64) bf16 pre-scaled by 0.125*log2(e). Kp (B,L,H,64). Vt (B*H,64,L).
__global__ __launch_bounds__(512, 2) void k_flash(const u16* __restrict__ Qp,
                                                  const u16* __restrict__ Kp,
                                                  const u16* __restrict__ Vt,
                                                  u16* __restrict__ ctx) {
  __shared__ __align__(16) u16 qs[256 * 64];   // 32KB Q stage; reused as P buffers
  __shared__ __align__(16) u16 ks[64 * 72];    // K tile, padded rows
  __shared__ __align__(16) u16 vs[64 * 72];    // V^T tile, padded rows
  const int t = threadIdx.x, lane = t & 63, quad = lane >> 4, l16 = lane & 15;
  const int wave = t >> 6;                      // 0..7
  const int bh = blockIdx.x & 31, b = bh >> 4, h = bh & 15;
  const int q0 = (blockIdx.x >> 5) * 256;
  const long gkbase = (long)b * 2097152 + h * 64;
  const long gvbase = (long)bh * 131072;
  const int srow = t >> 3, sc = t & 7;          // staging: row 0..63, 16B chunk 0..7

  // ---- startup: Q via async16 (XOR swizzle), K/V tile 0 via regs ----
  {
    long gq = (long)(b * 2048 + q0) * 1024 + h * 64;
    #pragma unroll
    for (int i = 0; i < 4; ++i) {
      int s = i * 512 + t;
      int row = s >> 3, pos = s & 7, c = pos ^ (row & 7);
      // per-wave contiguous dest: qs + s*8 == base + lane*16
      async16(qs + (long)s * 8, Qp + gq + (long)row * 1024 + c * 8);
    }
  }
  bf16x8 kreg = *(const bf16x8*)(Kp + gkbase + (long)srow * 1024 + sc * 8);
  bf16x8 vreg = *(const bf16x8*)(Vt + gvbase + (long)srow * 2048 + sc * 8);
  __syncthreads();  // Q visible

  bf16x8 qf[2][2];
  #pragma unroll
  for (int msub = 0; msub < 2; ++msub)
    #pragma unroll
    for (int kh = 0; kh < 2; ++kh) {
      int m = wave * 32 + msub * 16 + l16;
      int pos = (kh * 4 + quad) ^ (m & 7);
      qf[msub][kh] = *(const bf16x8*)(qs + m * 64 + pos * 8);
    }
  *(bf16x8*)(ks + srow * 72 + sc * 8) = kreg;
  *(bf16x8*)(vs + srow * 72 + sc * 8) = vreg;
  __syncthreads();  // K/V tile 0 visible; qs dead -> safe as P space

  u16* pw = qs + wave * 1152;  // per-wave P tile: 16 q-rows x 72 (one msub at a time)

  float lsum[2][4] = {};
  f32x4 o[2][4] = {};

  for (int kt = 0; kt < 32; ++kt) {
    // register prefetch of next K/V tile (in flight across this compute phase)
    if (kt < 31) {
      int kv0 = (kt + 1) * 64;
      kreg = *(const bf16x8*)(Kp + gkbase + (long)(kv0 + srow) * 1024 + sc * 8);
      vreg = *(const bf16x8*)(Vt + gvbase + kv0 + (long)srow * 2048 + sc * 8);
    }

    // K and V^T fragments (vector b128, <=2-way banks)
    bf16x8 kf[4][2], vf[4][2];
    #pragma unroll
    for (int nt = 0; nt < 4; ++nt)
      #pragma unroll
      for (int kh = 0; kh < 2; ++kh) {
        kf[nt][kh] = *(const bf16x8*)(ks + (nt * 16 + l16) * 72 + kh * 32 + quad * 8);
        vf[nt][kh] = *(const bf16x8*)(vs + (nt * 16 + l16) * 72 + kh * 32 + quad * 8);
      }

    #pragma unroll
    for (int msub = 0; msub < 2; ++msub) {
      // S(16x64) = Q @ K^T ; p = exp2(s); write P row-major [q][kv] to LDS
      #pragma unroll
      for (int nt = 0; nt < 4; ++nt) {
        f32x4 a = {};
        #pragma unroll
        for (int kh = 0; kh < 2; ++kh)
          a = __builtin_amdgcn_mfma_f32_16x16x32_bf16(qf[msub][kh], kf[nt][kh], a, 0, 0, 0);
        #pragma unroll
        for (int r = 0; r < 4; ++r) {
          float e = __builtin_amdgcn_exp2f(a[r]);
          lsum[msub][r] += e;
          pw[(quad * 4 + r) * 72 + nt * 16 + l16] = f2bf(e);
        }
      }
      // O(16x64) += P @ V : A-frag = contiguous b128 rows of P
      #pragma unroll
      for (int kh = 0; kh < 2; ++kh) {
        bf16x8 pa = *(const bf16x8*)(pw + l16 * 72 + kh * 32 + quad * 8);
        #pragma unroll
        for (int nt = 0; nt < 4; ++nt)
          o[msub][nt] = __builtin_amdgcn_mfma_f32_16x16x32_bf16(pa, vf[nt][kh], o[msub][nt], 0, 0, 0);
      }
    }

    __syncthreads();  // all waves done reading ks/vs (and prefetch drained)
    if (kt < 31) {
      *(bf16x8*)(ks + srow * 72 + sc * 8) = kreg;
      *(bf16x8*)(vs + srow * 72 + sc * 8) = vreg;
    }
    __syncthreads();  // next tile visible
  }

  // final l reduction across the 16 kv-lanes, then normalize + write
  #pragma unroll
  for (int msub = 0; msub < 2; ++msub)
    #pragma unroll
    for (int r = 0; r < 4; ++r) {
      float l = lsum[msub][r];
      #pragma unroll
      for (int d = 1; d < 16; d <<= 1) l += __shfl_xor(l, d);
      lsum[msub][r] = 1.0f / l;
    }
  #pragma unroll
  for (int msub = 0; msub < 2; ++msub)
    #pragma unroll
    for (int nt = 0; nt < 4; ++nt)
      #pragma unroll
      for (int r = 0; r < 4; ++r) {
        int q = q0 + wave * 32 + msub * 16 + quad * 4 + r;
        long idx = (long)(b * 2048 + q) * 1024 + h * 64 + nt * 16 + l16;
        ctx[idx] = f2bf(o[msub][nt][r] * lsum[msub][r]);
      }
}

extern "C" void kernel_launch(void* const* d_in, const int* in_sizes, int n_in,
                              void* d_out, int out_size, void* d_ws, size_t ws_size,
                              hipStream_t stream) {
  const float* query = (const float*)d_in[0];
  const float* key   = (const float*)d_in[1];
  const float* value = (const float*)d_in[2];
  const float* Wq    = (const float*)d_in[3];
  const float* Wk    = (const float*)d_in[4];
  const float* Wv    = (const float*)d_in[5];
  const float* out_w = (const float*)d_in[6];
  const float* out_b = (const float*)d_in[7];
  // d_in[8] = coupling: unused — per-head scalar bias is softmax-invariant.
  float* out = (float*)d_out;

  char* ws = (char*)d_ws;
  size_t off = 0;
  auto alloc = [&](size_t bytes) {
    void* p = ws + off;
    off += (bytes + 255) & ~(size_t)255;
    return p;
  };
  // qb,kb,vb contiguous; wtq,wtk,wtv contiguous; Qp,Kp,Vp contiguous —
  // k_cast3 / k_transpose_w / k_gemm_qkv index them by z-stride.
  u16* qb  = (u16*)alloc(4096L * 1024 * 2);
  u16* kb  = (u16*)alloc(4096L * 1024 * 2);
  u16* vb  = (u16*)alloc(4096L * 1024 * 2);
  u16* wtq = (u16*)alloc(1024L * 1024 * 2);
  u16* wtk = (u16*)alloc(1024L * 1024 * 2);
  u16* wtv = (u16*)alloc(1024L * 1024 * 2);
  u16* wto = (u16*)alloc(1024L * 1024 * 2);
  u16* Qp  = (u16*)alloc(4096L * 1024 * 2);
  u16* Kp  = (u16*)alloc(4096L * 1024 * 2);
  u16* Vp  = (u16*)alloc(4096L * 1024 * 2);
  u16* Vtb = (u16*)alloc(4096L * 1024 * 2);
  u16* ctx = qb;  // reuse: query-bf16 dead after Q projection
  (void)kb; (void)vb; (void)wtk; (void)wtv; (void)Kp; (void)Vp;

  // inputs -> bf16 (fused, grid.y selects tensor)
  k_cast3<<<dim3(4096, 3), 256, 0, stream>>>(Ptr3{query, key, value}, qb);

  // Wq/Wk/Wv -> Bt (NxK) bf16 (fused).  wt[w][h*64+k][d] = W[w][h][d][k]
  k_transpose_w<<<dim3(16, 1, 48), 256, 0, stream>>>(Ptr3{Wq, Wk, Wv}, wtq);
  // out_w (K x N) -> wto (N x K)
  k_transpose_bf16<<<dim3(16, 16, 1), 256, 0, stream>>>(out_w, 1, wto, 1024, 1024, 1, 0L, 0L);

  // fused Q,K,V projections (Q pre-scaled by 0.125*log2(e))
  k_gemm_qkv<<<dim3(8, 32, 3), 256, 0, stream>>>(qb, wtq, Qp, QSCALE);

  // V -> V^T per (b,h): Vt[bh][dim][l]
  k_transpose_bf16<<<dim3(32, 1, 32), 256, 0, stream>>>(Vp, 0, Vtb, 1024, 2048, 16, 64L, 2097152L);

  // attention: grid 256 = 8 q-tiles x 32 bh, bh in low 5 bits for XCD affinity
  k_flash<<<256, 512, 0, stream>>>(Qp, Kp, Vtb, ctx);

  // output projection + bias -> f32
  k_gemm_out<<<dim3(16, 32), 256, 0, stream>>>(ctx, wto, out, out_b);
}